// Round 8
// baseline (169.026 us; speedup 1.0000x reference)
//
#include <hip/hip_runtime.h>
#include <math.h>

#define BATCH 4
#define SEQ   1024
#define CH    1024
#define NH    16
#define HD    64
#define N3    3072

typedef unsigned short u16;
typedef unsigned int   u32;
typedef __attribute__((ext_vector_type(8))) __bf16 bf16x8;
typedef __attribute__((ext_vector_type(4))) float  f32x4;
typedef __attribute__((ext_vector_type(4))) u32    u32x4;

__device__ __forceinline__ u32 f2bf(float f) {
    u32 x = __float_as_uint(f);
    return (x + 0x7fffu + ((x >> 16) & 1u)) >> 16;   // RNE bf16
}

// async global -> LDS, 16B per lane; LDS dest = wave-uniform base + lane*16
__device__ __forceinline__ void gload_lds16(const u16* g, u16* l) {
    __builtin_amdgcn_global_load_lds(
        (const __attribute__((address_space(1))) void*)g,
        (__attribute__((address_space(3))) void*)l, 16, 0, 0);
}

// ---------------------------------------------------------------------------
// Fused prep: blocks [0,2048) cast x -> bf16; blocks [2048,6144) transpose
// both weight matrices to [N][1024] bf16.
// ---------------------------------------------------------------------------
__global__ __launch_bounds__(256) void prep_kernel(
    const float* __restrict__ x, const float* __restrict__ Wqkv,
    const float* __restrict__ Wproj,
    u16* __restrict__ xb, u16* __restrict__ wqT, u16* __restrict__ wpT)
{
    __shared__ float tile[32][33];
    const int blk = blockIdx.x;
    if (blk < 2048) {
        int i = (blk * 256 + threadIdx.x) * 8;
        float4 a = *(const float4*)&x[i];
        float4 b = *(const float4*)&x[i + 4];
        int4 p;
        p.x = (int)(f2bf(a.x) | (f2bf(a.y) << 16));
        p.y = (int)(f2bf(a.z) | (f2bf(a.w) << 16));
        p.z = (int)(f2bf(b.x) | (f2bf(b.y) << 16));
        p.w = (int)(f2bf(b.z) | (f2bf(b.w) << 16));
        *(int4*)&xb[i] = p;
        return;
    }
    const int bx2 = blk - 2048;          // 0..4095
    int nt = bx2 & 127;                  // n-tile: 0..95 qkv, 96..127 proj
    const int kt = bx2 >> 7;             // 0..31
    const float* W;
    u16* WT;
    int N;
    if (nt < 96) { W = Wqkv; WT = wqT; N = N3; }
    else         { nt -= 96; W = Wproj; WT = wpT; N = CH; }
    const int n0 = nt * 32, k0 = kt * 32;
    const int tx = threadIdx.x & 31, ty = threadIdx.x >> 5;
    #pragma unroll
    for (int p = 0; p < 4; p++)
        tile[ty + p * 8][tx] = W[(size_t)(k0 + ty + p * 8) * N + n0 + tx];
    __syncthreads();
    #pragma unroll
    for (int p = 0; p < 4; p++)
        WT[(size_t)(n0 + ty + p * 8) * CH + k0 + tx] = (u16)f2bf(tile[tx][ty + p * 8]);
}

// ---------------------------------------------------------------------------
// MFMA GEMM qkv: 128x128 tile, 4 waves, BK=32, global_load_lds staging.
// q,k -> [B][H][T][64]; v -> transposed [B][H][64][T] with packed 8B stores.
// ---------------------------------------------------------------------------
__global__ __launch_bounds__(256) void gemm_qkv_mfma(
    const u16* __restrict__ A, const u16* __restrict__ BT,
    u16* __restrict__ qb, u16* __restrict__ kbuf, u16* __restrict__ vtb)
{
    __shared__ __align__(16) u16 As[128 * 32];
    __shared__ __align__(16) u16 Bs[128 * 32];

    const int tid = threadIdx.x;
    const int lane = tid & 63;
    const int w = tid >> 6;
    const int wr = w >> 1, wc = w & 1;
    const int m0 = blockIdx.y * 128, n0 = blockIdx.x * 128;

    const int srow = lane >> 2;
    const int sk   = (lane & 3) * 8;
    const u16* gA0 = A  + (size_t)(m0 + w * 16 + srow) * CH + sk;
    const u16* gA1 = A  + (size_t)(m0 + (w + 4) * 16 + srow) * CH + sk;
    const u16* gB0 = BT + (size_t)(n0 + w * 16 + srow) * CH + sk;
    const u16* gB1 = BT + (size_t)(n0 + (w + 4) * 16 + srow) * CH + sk;
    u16* lA0 = As + w * 16 * 32;
    u16* lA1 = As + (w + 4) * 16 * 32;
    u16* lB0 = Bs + w * 16 * 32;
    u16* lB1 = Bs + (w + 4) * 16 * 32;

    const int ln = lane & 15, quad = lane >> 4;
    const int afo = (wr * 64 + ln) * 32 + quad * 8;
    const int bfo = (wc * 64 + ln) * 32 + quad * 8;

    f32x4 acc[4][4];
    #pragma unroll
    for (int i = 0; i < 4; i++)
        #pragma unroll
        for (int j = 0; j < 4; j++) acc[i][j] = (f32x4)(0.f);

    for (int k0 = 0; k0 < CH; k0 += 32) {
        __syncthreads();
        gload_lds16(gA0 + k0, lA0);
        gload_lds16(gA1 + k0, lA1);
        gload_lds16(gB0 + k0, lB0);
        gload_lds16(gB1 + k0, lB1);
        __syncthreads();
        bf16x8 af[4], bfr[4];
        #pragma unroll
        for (int mi = 0; mi < 4; mi++) af[mi]  = *(const bf16x8*)&As[afo + mi * 512];
        #pragma unroll
        for (int ni = 0; ni < 4; ni++) bfr[ni] = *(const bf16x8*)&Bs[bfo + ni * 512];
        #pragma unroll
        for (int mi = 0; mi < 4; mi++)
            #pragma unroll
            for (int ni = 0; ni < 4; ni++)
                acc[mi][ni] = __builtin_amdgcn_mfma_f32_16x16x32_bf16(
                    af[mi], bfr[ni], acc[mi][ni], 0, 0, 0);
    }

    const int which = (n0 >> 10);
    if (which == 2) {
        #pragma unroll
        for (int ni = 0; ni < 4; ni++) {
            const int n = n0 + wc * 64 + ni * 16 + ln;
            const int h = (n >> 6) & 15;
            const int d = n & 63;
            #pragma unroll
            for (int mi = 0; mi < 4; mi++) {
                const int m = m0 + wr * 64 + mi * 16 + quad * 4;
                const int b = m >> 10, t = m & 1023;
                int2 pv;
                pv.x = (int)(f2bf(acc[mi][ni][0]) | (f2bf(acc[mi][ni][1]) << 16));
                pv.y = (int)(f2bf(acc[mi][ni][2]) | (f2bf(acc[mi][ni][3]) << 16));
                *(int2*)&vtb[(((size_t)(b * NH + h)) * HD + d) * SEQ + t] = pv;
            }
        }
    } else {
        u16* dst = (which == 0) ? qb : kbuf;
        #pragma unroll
        for (int ni = 0; ni < 4; ni++) {
            const int n = n0 + wc * 64 + ni * 16 + ln;
            const int h = (n >> 6) & 15;
            const int d = n & 63;
            #pragma unroll
            for (int mi = 0; mi < 4; mi++) {
                #pragma unroll
                for (int r = 0; r < 4; r++) {
                    const int m = m0 + wr * 64 + mi * 16 + quad * 4 + r;
                    const int b = m >> 10, t = m & 1023;
                    dst[(((size_t)(b * NH + h)) * SEQ + t) * HD + d] =
                        (u16)f2bf(acc[mi][ni][r]);
                }
            }
        }
    }
}

// ---------------------------------------------------------------------------
// MFMA GEMM proj: 64x128 tile, fp32 out. span_loss folded into block (0,0).
// ---------------------------------------------------------------------------
__global__ __launch_bounds__(256) void gemm_proj_mfma(
    const u16* __restrict__ A, const u16* __restrict__ BT, float* __restrict__ out,
    const float* __restrict__ sp, float* __restrict__ loss_out)
{
    __shared__ __align__(16) u16 As[64 * 32];
    __shared__ __align__(16) u16 Bs[128 * 32];

    const int tid = threadIdx.x;
    const int lane = tid & 63;
    const int w = tid >> 6;
    const int wr = w >> 1, wc = w & 1;
    const int m0 = blockIdx.y * 64, n0 = blockIdx.x * 128;

    if (blockIdx.x == 0 && blockIdx.y == 0 && tid == 0) {
        float s = 0.f;
        #pragma unroll
        for (int h = 0; h < NH; h++) {
            float sig = 1.f / (1.f + __expf(-sp[h]));
            s += sig * 1024.f;
        }
        loss_out[0] = 2e-6f * s / (float)NH;
    }

    const int srow = lane >> 2;
    const int sk   = (lane & 3) * 8;
    const u16* gA0 = A  + (size_t)(m0 + w * 16 + srow) * CH + sk;
    const u16* gB0 = BT + (size_t)(n0 + w * 16 + srow) * CH + sk;
    const u16* gB1 = BT + (size_t)(n0 + (w + 4) * 16 + srow) * CH + sk;
    u16* lA0 = As + w * 16 * 32;
    u16* lB0 = Bs + w * 16 * 32;
    u16* lB1 = Bs + (w + 4) * 16 * 32;

    const int ln = lane & 15, quad = lane >> 4;
    const int afo = (wr * 32 + ln) * 32 + quad * 8;
    const int bfo = (wc * 64 + ln) * 32 + quad * 8;

    f32x4 acc[2][4];
    #pragma unroll
    for (int i = 0; i < 2; i++)
        #pragma unroll
        for (int j = 0; j < 4; j++) acc[i][j] = (f32x4)(0.f);

    for (int k0 = 0; k0 < CH; k0 += 32) {
        __syncthreads();
        gload_lds16(gA0 + k0, lA0);
        gload_lds16(gB0 + k0, lB0);
        gload_lds16(gB1 + k0, lB1);
        __syncthreads();
        bf16x8 af[2], bfr[4];
        #pragma unroll
        for (int mi = 0; mi < 2; mi++) af[mi]  = *(const bf16x8*)&As[afo + mi * 512];
        #pragma unroll
        for (int ni = 0; ni < 4; ni++) bfr[ni] = *(const bf16x8*)&Bs[bfo + ni * 512];
        #pragma unroll
        for (int mi = 0; mi < 2; mi++)
            #pragma unroll
            for (int ni = 0; ni < 4; ni++)
                acc[mi][ni] = __builtin_amdgcn_mfma_f32_16x16x32_bf16(
                    af[mi], bfr[ni], acc[mi][ni], 0, 0, 0);
    }

    #pragma unroll
    for (int ni = 0; ni < 4; ni++) {
        const int n = n0 + wc * 64 + ni * 16 + ln;
        #pragma unroll
        for (int mi = 0; mi < 2; mi++) {
            #pragma unroll
            for (int r = 0; r < 4; r++) {
                const int m = m0 + wr * 32 + mi * 16 + quad * 4 + r;
                out[(size_t)m * CH + n] = acc[mi][ni][r];
            }
        }
    }
}

// ---------------------------------------------------------------------------
// MFMA flash attention v4: 128-row Q blocks (grid 512, all co-resident),
// double-buffered K/V staging with ONE barrier per j-tile (prefetch issued
// right after the barrier, compute hides the load latency).
// Each wave owns two 16-row halves (rb0 = it0+w*16, rb1 = it0+64+w*16).
// ---------------------------------------------------------------------------
__global__ __launch_bounds__(256) void attn_mfma_kernel(
    const u16* __restrict__ qg, const u16* __restrict__ kg,
    const u16* __restrict__ vt,
    const float* __restrict__ span_params, const float* __restrict__ stride_params,
    u16* __restrict__ yb)
{
    __shared__ __align__(16) u16 Ks[2][64 * 64];     // [j][d], chunk c at slot c^(j&7)
    __shared__ __align__(16) u16 Vs[2][64 * 64];     // [d][t], chunk c at slot c^(d&7)
    __shared__ __align__(16) u16 Ps[4][2][16 * 64];  // per-wave, per-half P

    const int tid  = threadIdx.x;
    const int lane = tid & 63;
    const int w    = tid >> 6;
    const int ln   = lane & 15, quad = lane >> 4;
    const int lm7  = ln & 7;

    const int blk = blockIdx.x;
    const int bh  = blk & 63;
    const int itile = 7 - (blk >> 6);        // heavy q-tiles first
    const int h   = bh & (NH - 1);
    const int b   = bh >> 4;
    const int it0 = itile << 7;

    const float span  = 1024.f / (1.f + __expf(-span_params[h]));
    const float limit = 32.f + span;
    const float e0 = __expf(stride_params[2 * h + 0]);
    const float e1 = __expf(stride_params[2 * h + 1]);
    const float swO = e0 / (e0 + e1);        // odd-rel factor; even-rel = 1
    const float c1 = limit * (1.f / 32.f);

    const size_t hb  = (size_t)bh * SEQ;
    const size_t hvt = (size_t)bh * HD;

    // Q A-frags for both halves
    const int rb0 = it0 + (w << 4);
    const int rb1 = rb0 + 64;
    const u16* qp0 = qg + (hb + rb0 + ln) * HD + quad * 8;
    const u16* qp1 = qg + (hb + rb1 + ln) * HD + quad * 8;
    bf16x8 aqA[2], aqB[2];
    aqA[0] = *(const bf16x8*)qp0;  aqB[0] = *(const bf16x8*)(qp0 + 32);
    aqA[1] = *(const bf16x8*)qp1;  aqB[1] = *(const bf16x8*)(qp1 + 32);

    u32x4 onesw; onesw.x = onesw.y = onesw.z = onesw.w = 0x3f803f80u;
    const bf16x8 onesf = __builtin_bit_cast(bf16x8, onesw);

    f32x4 acc_o[2][4];
    f32x4 acc_s[2];
    #pragma unroll
    for (int p = 0; p < 2; p++) {
        acc_s[p] = (f32x4)(0.f);
        #pragma unroll
        for (int di = 0; di < 4; di++) acc_o[p][di] = (f32x4)(0.f);
    }

    int jmin = it0 - (int)limit - 1;
    if (jmin < 0) jmin = 0;
    const int jt0 = jmin & ~63;
    const int last = it0 + 64;               // tile containing row it0+127

    // staging: wave w covers rows w*8..w*8+7 (+32 in second call)
    const int srow = lane >> 3;
    const int schk = lane & 7;
    const int cs   = schk ^ srow;
    const int ra   = w * 8 + srow;
    const u16* pk0 = kg + (hb + ra) * HD + cs * 8;
    const u16* pk1 = pk0 + 32 * HD;
    const u16* pv0 = vt + (hvt + ra) * SEQ + cs * 8;
    const u16* pv1 = pv0 + 32 * SEQ;

    // prologue: stage first tile into buffer 0
    gload_lds16(pk0 + (size_t)jt0 * HD, &Ks[0][w * 512]);
    gload_lds16(pk1 + (size_t)jt0 * HD, &Ks[0][2048 + w * 512]);
    gload_lds16(pv0 + jt0,              &Vs[0][w * 512]);
    gload_lds16(pv1 + jt0,              &Vs[0][2048 + w * 512]);

    int cur = 0;
    for (int jt = jt0; jt <= last; jt += 64, cur ^= 1) {
        __syncthreads();   // tile jt complete; alt buffer's old readers done

        const int nxt = jt + 64;
        if (nxt <= last) {
            gload_lds16(pk0 + (size_t)nxt * HD, &Ks[cur ^ 1][w * 512]);
            gload_lds16(pk1 + (size_t)nxt * HD, &Ks[cur ^ 1][2048 + w * 512]);
            gload_lds16(pv0 + nxt,              &Vs[cur ^ 1][w * 512]);
            gload_lds16(pv1 + nxt,              &Vs[cur ^ 1][2048 + w * 512]);
        }

        const u16* Kc = Ks[cur];
        const u16* Vc = Vs[cur];

        #pragma unroll
        for (int p = 0; p < 2; p++) {
            const int row_base = (p == 0) ? rb0 : rb1;
            bool sk[4];
            #pragma unroll
            for (int ni = 0; ni < 4; ni++) {
                const int col0 = jt + ni * 16;
                sk[ni] = (row_base + 15 < col0) ||
                         ((float)(row_base - (col0 + 15)) >= limit);
            }
            const bool nz0 = !sk[0] || !sk[1];
            const bool nz1 = !sk[2] || !sk[3];
            if (!nz0 && !nz1) continue;

            u16* Psw = &Ps[w][p][0];
            const bf16x8 qa = aqA[p], qb_ = aqB[p];

            #pragma unroll
            for (int ni = 0; ni < 4; ni++) {
                const int col0 = jt + ni * 16;
                const int cbase = ni * 2 + (ln >> 3);
                if (sk[ni]) {
                    if ((ni < 2) ? nz0 : nz1) {
                        #pragma unroll
                        for (int r = 0; r < 4; r++) {
                            const int il = quad * 4 + r;
                            Psw[il * 64 + (cbase ^ (il & 7)) * 8 + lm7] = 0;
                        }
                    }
                    continue;
                }
                const int krow = ni * 16 + ln;
                bf16x8 bk0 = *(const bf16x8*)&Kc[krow * 64 + ((quad ^ lm7) * 8)];
                bf16x8 bk1 = *(const bf16x8*)&Kc[krow * 64 + (((quad + 4) ^ lm7) * 8)];
                f32x4 s = __builtin_amdgcn_mfma_f32_16x16x32_bf16(qa, bk0, (f32x4)(0.f), 0, 0, 0);
                s = __builtin_amdgcn_mfma_f32_16x16x32_bf16(qb_, bk1, s, 0, 0, 0);
                #pragma unroll
                for (int r = 0; r < 4; r++) {
                    const int il  = quad * 4 + r;
                    const int rel = (row_base + il) - (col0 + ln);
                    float clip = fminf(fmaxf(fmaf((float)rel, -(1.f / 32.f), c1), 0.f), 1.f);
                    float fac  = (rel & 1) ? swO : 1.0f;
                    float wt   = (rel < 0) ? 0.f : clip * fac;
                    float wv   = __expf(s[r] * 0.125f) * wt;
                    Psw[il * 64 + (cbase ^ (il & 7)) * 8 + lm7] = (u16)f2bf(wv);
                }
            }

            if (nz0) {
                bf16x8 ap0 = *(const bf16x8*)&Psw[ln * 64 + (quad ^ lm7) * 8];
                acc_s[p] = __builtin_amdgcn_mfma_f32_16x16x32_bf16(ap0, onesf, acc_s[p], 0, 0, 0);
                #pragma unroll
                for (int di = 0; di < 4; di++) {
                    const int vrow = di * 16 + ln;
                    bf16x8 bv0 = *(const bf16x8*)&Vc[vrow * 64 + ((quad ^ lm7) * 8)];
                    acc_o[p][di] = __builtin_amdgcn_mfma_f32_16x16x32_bf16(ap0, bv0, acc_o[p][di], 0, 0, 0);
                }
            }
            if (nz1) {
                bf16x8 ap1 = *(const bf16x8*)&Psw[ln * 64 + ((quad + 4) ^ lm7) * 8];
                acc_s[p] = __builtin_amdgcn_mfma_f32_16x16x32_bf16(ap1, onesf, acc_s[p], 0, 0, 0);
                #pragma unroll
                for (int di = 0; di < 4; di++) {
                    const int vrow = di * 16 + ln;
                    bf16x8 bv1 = *(const bf16x8*)&Vc[vrow * 64 + (((quad + 4) ^ lm7) * 8)];
                    acc_o[p][di] = __builtin_amdgcn_mfma_f32_16x16x32_bf16(ap1, bv1, acc_o[p][di], 0, 0, 0);
                }
            }
        }
    }

    #pragma unroll
    for (int p = 0; p < 2; p++) {
        const int row_base = (p == 0) ? rb0 : rb1;
        #pragma unroll
        for (int r = 0; r < 4; r++) {
            const int t = row_base + quad * 4 + r;
            const float inv = 1.f / acc_s[p][r];
            const size_t rowoff = ((size_t)(b * SEQ + t)) * CH + h * HD;
            #pragma unroll
            for (int di = 0; di < 4; di++)
                yb[rowoff + di * 16 + ln] = (u16)f2bf(acc_o[p][di][r] * inv);
        }
    }
}

extern "C" void kernel_launch(void* const* d_in, const int* in_sizes, int n_in,
                              void* d_out, int out_size, void* d_ws, size_t ws_size,
                              hipStream_t stream)
{
    const float* x            = (const float*)d_in[0];
    const float* Wqkv         = (const float*)d_in[1];
    const float* Wproj        = (const float*)d_in[2];
    const float* span_params  = (const float*)d_in[3];
    const float* stride_param = (const float*)d_in[4];
    float* out = (float*)d_out;

    const size_t SZ = (size_t)BATCH * NH * SEQ * HD;  // 4,194,304
    u16* base = (u16*)d_ws;
    u16* qb  = base;                    // bf16 [B][H][T][64]
    u16* kb  = qb + SZ;
    u16* vtb = kb + SZ;                 // bf16 [B][H][64][T]
    u16* yb  = vtb + SZ;                // bf16 [B][T][C]
    u16* xb  = yb + SZ;                 // bf16 x
    u16* wqT = xb + SZ;                 // bf16 [3072][1024]
    u16* wpT = wqT + (size_t)CH * N3;   // bf16 [1024][1024]

    prep_kernel<<<dim3(6144), 256, 0, stream>>>(x, Wqkv, Wproj, xb, wqT, wpT);

    gemm_qkv_mfma<<<dim3(N3 / 128, (BATCH * SEQ) / 128), 256, 0, stream>>>(
        xb, wqT, qb, kb, vtb);

    attn_mfma_kernel<<<dim3(BATCH * NH * (SEQ / 128)), 256, 0, stream>>>(
        qb, kb, vtb, span_params, stride_param, yb);

    gemm_proj_mfma<<<dim3(CH / 128, (BATCH * SEQ) / 64), 256, 0, stream>>>(
        yb, wpT, out, span_params, out + SZ);
}

// Round 9
// 161.205 us; speedup vs baseline: 1.0485x; 1.0485x over previous
//
#include <hip/hip_runtime.h>
#include <math.h>

#define BATCH 4
#define SEQ   1024
#define CH    1024
#define NH    16
#define HD    64
#define N3    3072

typedef unsigned short u16;
typedef unsigned int   u32;
typedef __attribute__((ext_vector_type(8))) __bf16 bf16x8;
typedef __attribute__((ext_vector_type(4))) float  f32x4;
typedef __attribute__((ext_vector_type(4))) u32    u32x4;

__device__ __forceinline__ u32 f2bf(float f) {
    u32 x = __float_as_uint(f);
    return (x + 0x7fffu + ((x >> 16) & 1u)) >> 16;   // RNE bf16
}

// async global -> LDS, 16B per lane; LDS dest = wave-uniform base + lane*16
__device__ __forceinline__ void gload_lds16(const u16* g, u16* l) {
    __builtin_amdgcn_global_load_lds(
        (const __attribute__((address_space(1))) void*)g,
        (__attribute__((address_space(3))) void*)l, 16, 0, 0);
}

// ---------------------------------------------------------------------------
// Fused prep: blocks [0,2048) cast x -> bf16; blocks [2048,6144) transpose
// both weight matrices to [N][1024] bf16.
// ---------------------------------------------------------------------------
__global__ __launch_bounds__(256) void prep_kernel(
    const float* __restrict__ x, const float* __restrict__ Wqkv,
    const float* __restrict__ Wproj,
    u16* __restrict__ xb, u16* __restrict__ wqT, u16* __restrict__ wpT)
{
    __shared__ float tile[32][33];
    const int blk = blockIdx.x;
    if (blk < 2048) {
        int i = (blk * 256 + threadIdx.x) * 8;
        float4 a = *(const float4*)&x[i];
        float4 b = *(const float4*)&x[i + 4];
        int4 p;
        p.x = (int)(f2bf(a.x) | (f2bf(a.y) << 16));
        p.y = (int)(f2bf(a.z) | (f2bf(a.w) << 16));
        p.z = (int)(f2bf(b.x) | (f2bf(b.y) << 16));
        p.w = (int)(f2bf(b.z) | (f2bf(b.w) << 16));
        *(int4*)&xb[i] = p;
        return;
    }
    const int bx2 = blk - 2048;          // 0..4095
    int nt = bx2 & 127;                  // n-tile: 0..95 qkv, 96..127 proj
    const int kt = bx2 >> 7;             // 0..31
    const float* W;
    u16* WT;
    int N;
    if (nt < 96) { W = Wqkv; WT = wqT; N = N3; }
    else         { nt -= 96; W = Wproj; WT = wpT; N = CH; }
    const int n0 = nt * 32, k0 = kt * 32;
    const int tx = threadIdx.x & 31, ty = threadIdx.x >> 5;
    #pragma unroll
    for (int p = 0; p < 4; p++)
        tile[ty + p * 8][tx] = W[(size_t)(k0 + ty + p * 8) * N + n0 + tx];
    __syncthreads();
    #pragma unroll
    for (int p = 0; p < 4; p++)
        WT[(size_t)(n0 + ty + p * 8) * CH + k0 + tx] = (u16)f2bf(tile[tx][ty + p * 8]);
}

// ---------------------------------------------------------------------------
// MFMA GEMM qkv: 128x128 tile, 4 waves, BK=32, global_load_lds staging.
// q,k -> [B][H][T][64]; v -> transposed [B][H][64][T] with packed 8B stores.
// ---------------------------------------------------------------------------
__global__ __launch_bounds__(256) void gemm_qkv_mfma(
    const u16* __restrict__ A, const u16* __restrict__ BT,
    u16* __restrict__ qb, u16* __restrict__ kbuf, u16* __restrict__ vtb)
{
    __shared__ __align__(16) u16 As[128 * 32];
    __shared__ __align__(16) u16 Bs[128 * 32];

    const int tid = threadIdx.x;
    const int lane = tid & 63;
    const int w = tid >> 6;
    const int wr = w >> 1, wc = w & 1;
    const int m0 = blockIdx.y * 128, n0 = blockIdx.x * 128;

    const int srow = lane >> 2;
    const int sk   = (lane & 3) * 8;
    const u16* gA0 = A  + (size_t)(m0 + w * 16 + srow) * CH + sk;
    const u16* gA1 = A  + (size_t)(m0 + (w + 4) * 16 + srow) * CH + sk;
    const u16* gB0 = BT + (size_t)(n0 + w * 16 + srow) * CH + sk;
    const u16* gB1 = BT + (size_t)(n0 + (w + 4) * 16 + srow) * CH + sk;
    u16* lA0 = As + w * 16 * 32;
    u16* lA1 = As + (w + 4) * 16 * 32;
    u16* lB0 = Bs + w * 16 * 32;
    u16* lB1 = Bs + (w + 4) * 16 * 32;

    const int ln = lane & 15, quad = lane >> 4;
    const int afo = (wr * 64 + ln) * 32 + quad * 8;
    const int bfo = (wc * 64 + ln) * 32 + quad * 8;

    f32x4 acc[4][4];
    #pragma unroll
    for (int i = 0; i < 4; i++)
        #pragma unroll
        for (int j = 0; j < 4; j++) acc[i][j] = (f32x4)(0.f);

    for (int k0 = 0; k0 < CH; k0 += 32) {
        __syncthreads();
        gload_lds16(gA0 + k0, lA0);
        gload_lds16(gA1 + k0, lA1);
        gload_lds16(gB0 + k0, lB0);
        gload_lds16(gB1 + k0, lB1);
        __syncthreads();
        bf16x8 af[4], bfr[4];
        #pragma unroll
        for (int mi = 0; mi < 4; mi++) af[mi]  = *(const bf16x8*)&As[afo + mi * 512];
        #pragma unroll
        for (int ni = 0; ni < 4; ni++) bfr[ni] = *(const bf16x8*)&Bs[bfo + ni * 512];
        #pragma unroll
        for (int mi = 0; mi < 4; mi++)
            #pragma unroll
            for (int ni = 0; ni < 4; ni++)
                acc[mi][ni] = __builtin_amdgcn_mfma_f32_16x16x32_bf16(
                    af[mi], bfr[ni], acc[mi][ni], 0, 0, 0);
    }

    const int which = (n0 >> 10);
    if (which == 2) {
        #pragma unroll
        for (int ni = 0; ni < 4; ni++) {
            const int n = n0 + wc * 64 + ni * 16 + ln;
            const int h = (n >> 6) & 15;
            const int d = n & 63;
            #pragma unroll
            for (int mi = 0; mi < 4; mi++) {
                const int m = m0 + wr * 64 + mi * 16 + quad * 4;
                const int b = m >> 10, t = m & 1023;
                int2 pv;
                pv.x = (int)(f2bf(acc[mi][ni][0]) | (f2bf(acc[mi][ni][1]) << 16));
                pv.y = (int)(f2bf(acc[mi][ni][2]) | (f2bf(acc[mi][ni][3]) << 16));
                *(int2*)&vtb[(((size_t)(b * NH + h)) * HD + d) * SEQ + t] = pv;
            }
        }
    } else {
        u16* dst = (which == 0) ? qb : kbuf;
        #pragma unroll
        for (int ni = 0; ni < 4; ni++) {
            const int n = n0 + wc * 64 + ni * 16 + ln;
            const int h = (n >> 6) & 15;
            const int d = n & 63;
            #pragma unroll
            for (int mi = 0; mi < 4; mi++) {
                #pragma unroll
                for (int r = 0; r < 4; r++) {
                    const int m = m0 + wr * 64 + mi * 16 + quad * 4 + r;
                    const int b = m >> 10, t = m & 1023;
                    dst[(((size_t)(b * NH + h)) * SEQ + t) * HD + d] =
                        (u16)f2bf(acc[mi][ni][r]);
                }
            }
        }
    }
}

// ---------------------------------------------------------------------------
// MFMA GEMM proj: 64x128 tile, fp32 out. span_loss folded into block (0,0).
// ---------------------------------------------------------------------------
__global__ __launch_bounds__(256) void gemm_proj_mfma(
    const u16* __restrict__ A, const u16* __restrict__ BT, float* __restrict__ out,
    const float* __restrict__ sp, float* __restrict__ loss_out)
{
    __shared__ __align__(16) u16 As[64 * 32];
    __shared__ __align__(16) u16 Bs[128 * 32];

    const int tid = threadIdx.x;
    const int lane = tid & 63;
    const int w = tid >> 6;
    const int wr = w >> 1, wc = w & 1;
    const int m0 = blockIdx.y * 64, n0 = blockIdx.x * 128;

    if (blockIdx.x == 0 && blockIdx.y == 0 && tid == 0) {
        float s = 0.f;
        #pragma unroll
        for (int h = 0; h < NH; h++) {
            float sig = 1.f / (1.f + __expf(-sp[h]));
            s += sig * 1024.f;
        }
        loss_out[0] = 2e-6f * s / (float)NH;
    }

    const int srow = lane >> 2;
    const int sk   = (lane & 3) * 8;
    const u16* gA0 = A  + (size_t)(m0 + w * 16 + srow) * CH + sk;
    const u16* gB0 = BT + (size_t)(n0 + w * 16 + srow) * CH + sk;
    const u16* gB1 = BT + (size_t)(n0 + (w + 4) * 16 + srow) * CH + sk;
    u16* lA0 = As + w * 16 * 32;
    u16* lB0 = Bs + w * 16 * 32;
    u16* lB1 = Bs + (w + 4) * 16 * 32;

    const int ln = lane & 15, quad = lane >> 4;
    const int afo = (wr * 32 + ln) * 32 + quad * 8;
    const int bfo = (wc * 64 + ln) * 32 + quad * 8;

    f32x4 acc[2][4];
    #pragma unroll
    for (int i = 0; i < 2; i++)
        #pragma unroll
        for (int j = 0; j < 4; j++) acc[i][j] = (f32x4)(0.f);

    for (int k0 = 0; k0 < CH; k0 += 32) {
        __syncthreads();
        gload_lds16(gA0 + k0, lA0);
        gload_lds16(gB0 + k0, lB0);
        gload_lds16(gB1 + k0, lB1);
        __syncthreads();
        bf16x8 af[2], bfr[4];
        #pragma unroll
        for (int mi = 0; mi < 2; mi++) af[mi]  = *(const bf16x8*)&As[afo + mi * 512];
        #pragma unroll
        for (int ni = 0; ni < 4; ni++) bfr[ni] = *(const bf16x8*)&Bs[bfo + ni * 512];
        #pragma unroll
        for (int mi = 0; mi < 2; mi++)
            #pragma unroll
            for (int ni = 0; ni < 4; ni++)
                acc[mi][ni] = __builtin_amdgcn_mfma_f32_16x16x32_bf16(
                    af[mi], bfr[ni], acc[mi][ni], 0, 0, 0);
    }

    #pragma unroll
    for (int ni = 0; ni < 4; ni++) {
        const int n = n0 + wc * 64 + ni * 16 + ln;
        #pragma unroll
        for (int mi = 0; mi < 2; mi++) {
            #pragma unroll
            for (int r = 0; r < 4; r++) {
                const int m = m0 + wr * 32 + mi * 16 + quad * 4 + r;
                out[(size_t)m * CH + n] = acc[mi][ni][r];
            }
        }
    }
}

// ---------------------------------------------------------------------------
// MFMA flash attention v5: R6's v3 structure (64-row Q blocks, grid 1024,
// 4 blocks/CU) + double-buffered K/V staging -> ONE barrier per j-tile.
// Prefetch for tile jt+64 issued right after the barrier; ~36 MFMAs + exp
// VALU of compute hide its latency before the next barrier's vmcnt drain.
// ---------------------------------------------------------------------------
__global__ __launch_bounds__(256) void attn_mfma_kernel(
    const u16* __restrict__ qg, const u16* __restrict__ kg,
    const u16* __restrict__ vt,
    const float* __restrict__ span_params, const float* __restrict__ stride_params,
    u16* __restrict__ yb)
{
    __shared__ __align__(16) u16 Ks[2][64 * 64];   // [j][d], chunk c at slot c^(j&7)
    __shared__ __align__(16) u16 Vs[2][64 * 64];   // [d][t], chunk c at slot c^(d&7)
    __shared__ __align__(16) u16 Ps[4][16 * 64];   // per-wave P, XOR-swizzled

    const int tid  = threadIdx.x;
    const int lane = tid & 63;
    const int w    = tid >> 6;
    const int ln   = lane & 15, quad = lane >> 4;
    const int lm7  = ln & 7;

    const int blk = blockIdx.x;
    const int bh  = blk & 63;                // same-it blocks contiguous,
    const int it  = 15 - (blk >> 6);         // heavy q-tiles dispatched first
    const int h   = bh & (NH - 1);
    const int b   = bh >> 4;
    const int it0 = it << 6;
    const int row_base = it0 + (w << 4);

    const float span  = 1024.f / (1.f + __expf(-span_params[h]));
    const float limit = 32.f + span;
    const float e0 = __expf(stride_params[2 * h + 0]);
    const float e1 = __expf(stride_params[2 * h + 1]);
    const float swO = e0 / (e0 + e1);        // odd-rel factor; even-rel = 1
    const float c1 = limit * (1.f / 32.f);   // clip = clamp(c1 - rel/32, 0, 1)

    const size_t hb  = (size_t)bh * SEQ;
    const size_t hvt = (size_t)bh * HD;

    const u16* qp = qg + (hb + row_base + ln) * HD + quad * 8;
    bf16x8 aq0 = *(const bf16x8*)qp;
    bf16x8 aq1 = *(const bf16x8*)(qp + 32);

    u32x4 onesw; onesw.x = onesw.y = onesw.z = onesw.w = 0x3f803f80u;
    const bf16x8 onesf = __builtin_bit_cast(bf16x8, onesw);

    f32x4 acc_o[4];
    #pragma unroll
    for (int di = 0; di < 4; di++) acc_o[di] = (f32x4)(0.f);
    f32x4 acc_s = (f32x4)(0.f);

    int jmin = it0 - (int)limit - 1;
    if (jmin < 0) jmin = 0;
    const int jt0 = jmin & ~63;

    const int srow = lane >> 3;              // 0..7
    const int schk = lane & 7;
    const int cs   = schk ^ srow;            // swizzled source chunk
    const int ra   = w * 8 + srow;           // 0..31
    const u16* pk0 = kg + (hb + ra) * HD + cs * 8;
    const u16* pk1 = pk0 + 32 * HD;
    const u16* pv0 = vt + (hvt + ra) * SEQ + cs * 8;
    const u16* pv1 = pv0 + 32 * SEQ;

    u16* Psw = Ps[w];

    // prologue: stage first tile into buffer 0
    gload_lds16(pk0 + (size_t)jt0 * HD, &Ks[0][w * 512]);
    gload_lds16(pk1 + (size_t)jt0 * HD, &Ks[0][2048 + w * 512]);
    gload_lds16(pv0 + jt0,              &Vs[0][w * 512]);
    gload_lds16(pv1 + jt0,              &Vs[0][2048 + w * 512]);

    int cur = 0;
    for (int jt = jt0; jt <= it0; jt += 64, cur ^= 1) {
        __syncthreads();   // tile jt staged; prior readers of alt buffer done

        const int nxt = jt + 64;
        if (nxt <= it0) {
            gload_lds16(pk0 + (size_t)nxt * HD, &Ks[cur ^ 1][w * 512]);
            gload_lds16(pk1 + (size_t)nxt * HD, &Ks[cur ^ 1][2048 + w * 512]);
            gload_lds16(pv0 + nxt,              &Vs[cur ^ 1][w * 512]);
            gload_lds16(pv1 + nxt,              &Vs[cur ^ 1][2048 + w * 512]);
        }

        const u16* Kc = Ks[cur];
        const u16* Vc = Vs[cur];

        bool sk[4];
        #pragma unroll
        for (int ni = 0; ni < 4; ni++) {
            const int col0 = jt + ni * 16;
            sk[ni] = (row_base + 15 < col0) ||
                     ((float)(row_base - (col0 + 15)) >= limit);
        }
        const bool nz0 = !sk[0] || !sk[1];
        const bool nz1 = !sk[2] || !sk[3];

        #pragma unroll
        for (int ni = 0; ni < 4; ni++) {
            const int col0 = jt + ni * 16;
            const int cbase = ni * 2 + (ln >> 3);
            if (sk[ni]) {
                if ((ni < 2) ? nz0 : nz1) {
                    #pragma unroll
                    for (int r = 0; r < 4; r++) {
                        const int il = quad * 4 + r;
                        Psw[il * 64 + (cbase ^ (il & 7)) * 8 + lm7] = 0;
                    }
                }
                continue;
            }
            const int krow = ni * 16 + ln;
            bf16x8 bk0 = *(const bf16x8*)&Kc[krow * 64 + ((quad ^ lm7) * 8)];
            bf16x8 bk1 = *(const bf16x8*)&Kc[krow * 64 + (((quad + 4) ^ lm7) * 8)];
            f32x4 s = __builtin_amdgcn_mfma_f32_16x16x32_bf16(aq0, bk0, (f32x4)(0.f), 0, 0, 0);
            s = __builtin_amdgcn_mfma_f32_16x16x32_bf16(aq1, bk1, s, 0, 0, 0);
            #pragma unroll
            for (int r = 0; r < 4; r++) {
                const int il  = quad * 4 + r;
                const int rel = (row_base + il) - (col0 + ln);
                float clip = fminf(fmaxf(fmaf((float)rel, -(1.f / 32.f), c1), 0.f), 1.f);
                float fac  = (rel & 1) ? swO : 1.0f;
                float wt   = (rel < 0) ? 0.f : clip * fac;
                float wv   = __expf(s[r] * 0.125f) * wt;
                Psw[il * 64 + (cbase ^ (il & 7)) * 8 + lm7] = (u16)f2bf(wv);
            }
        }

        if (nz0) {
            bf16x8 ap0 = *(const bf16x8*)&Psw[ln * 64 + (quad ^ lm7) * 8];
            acc_s = __builtin_amdgcn_mfma_f32_16x16x32_bf16(ap0, onesf, acc_s, 0, 0, 0);
            #pragma unroll
            for (int di = 0; di < 4; di++) {
                const int vrow = di * 16 + ln;
                bf16x8 bv0 = *(const bf16x8*)&Vc[vrow * 64 + ((quad ^ lm7) * 8)];
                acc_o[di] = __builtin_amdgcn_mfma_f32_16x16x32_bf16(ap0, bv0, acc_o[di], 0, 0, 0);
            }
        }
        if (nz1) {
            bf16x8 ap1 = *(const bf16x8*)&Psw[ln * 64 + ((quad + 4) ^ lm7) * 8];
            acc_s = __builtin_amdgcn_mfma_f32_16x16x32_bf16(ap1, onesf, acc_s, 0, 0, 0);
            #pragma unroll
            for (int di = 0; di < 4; di++) {
                const int vrow = di * 16 + ln;
                bf16x8 bv1 = *(const bf16x8*)&Vc[vrow * 64 + (((quad + 4) ^ lm7) * 8)];
                acc_o[di] = __builtin_amdgcn_mfma_f32_16x16x32_bf16(ap1, bv1, acc_o[di], 0, 0, 0);
            }
        }
    }

    #pragma unroll
    for (int r = 0; r < 4; r++) {
        const int t = row_base + quad * 4 + r;
        const float inv = 1.f / acc_s[r];
        const size_t rowoff = ((size_t)(b * SEQ + t)) * CH + h * HD;
        #pragma unroll
        for (int di = 0; di < 4; di++)
            yb[rowoff + di * 16 + ln] = (u16)f2bf(acc_o[di][r] * inv);
    }
}

extern "C" void kernel_launch(void* const* d_in, const int* in_sizes, int n_in,
                              void* d_out, int out_size, void* d_ws, size_t ws_size,
                              hipStream_t stream)
{
    const float* x            = (const float*)d_in[0];
    const float* Wqkv         = (const float*)d_in[1];
    const float* Wproj        = (const float*)d_in[2];
    const float* span_params  = (const float*)d_in[3];
    const float* stride_param = (const float*)d_in[4];
    float* out = (float*)d_out;

    const size_t SZ = (size_t)BATCH * NH * SEQ * HD;  // 4,194,304
    u16* base = (u16*)d_ws;
    u16* qb  = base;                    // bf16 [B][H][T][64]
    u16* kb  = qb + SZ;
    u16* vtb = kb + SZ;                 // bf16 [B][H][64][T]
    u16* yb  = vtb + SZ;                // bf16 [B][T][C]
    u16* xb  = yb + SZ;                 // bf16 x
    u16* wqT = xb + SZ;                 // bf16 [3072][1024]
    u16* wpT = wqT + (size_t)CH * N3;   // bf16 [1024][1024]

    prep_kernel<<<dim3(6144), 256, 0, stream>>>(x, Wqkv, Wproj, xb, wqT, wpT);

    gemm_qkv_mfma<<<dim3(N3 / 128, (BATCH * SEQ) / 128), 256, 0, stream>>>(
        xb, wqT, qb, kb, vtb);

    attn_mfma_kernel<<<dim3(BATCH * NH * (SEQ / 64)), 256, 0, stream>>>(
        qb, kb, vtb, span_params, stride_param, yb);

    gemm_proj_mfma<<<dim3(CH / 128, (BATCH * SEQ) / 64), 256, 0, stream>>>(
        yb, wpT, out, span_params, out + SZ);
}